// Round 4
// baseline (366.645 us; speedup 1.0000x reference)
//
#include <hip/hip_runtime.h>

// DGPE ODE RHS, 6-point periodic stencil on 192^3 lattice, fp32.
// R4: float4 along z + y-marching sliding window (4 rows/thread).
//  - center/ym/yp rows reused in registers: fewer loads per site
//  - unrolled 4-step loop -> 4 independent load batches in flight (MLP)
//  - no XCD swizzle (R3 regression), no nontemporal (R2 corruption)

#define LDIM 192
#define LSQ  (LDIM * LDIM)          // 36864
#define NTOT (LDIM * LDIM * LDIM)   // 7077888
#define HSTEP 4                     // y-rows marched per thread
#define ZCH  (LDIM / 4)             // 48 float4-chunks per row
#define YGRP (LDIM / HSTEP)         // 48 y-groups
#define NTHREADS (LDIM * YGRP * ZCH)  // 442368
#define NBLK (NTHREADS / 256)         // 1728

typedef float f4 __attribute__((ext_vector_type(4)));

__global__ __launch_bounds__(256, 4) void dgpe_kernel(
    const float* __restrict__ y,
    const float* __restrict__ Jarr,
    const float* __restrict__ aniso,
    const float* __restrict__ gam,
    const float* __restrict__ hdx,
    const float* __restrict__ hdy,
    const float* __restrict__ beta,
    const float* __restrict__ edis,
    float* __restrict__ out)
{
    const int t = blockIdx.x * 256 + threadIdx.x;

    // t = (a*48 + yg)*48 + zc : zc fastest for coalescing
    const unsigned ut = (unsigned)t;
    const unsigned zc = ut % 48u;
    const unsigned r  = ut / 48u;
    const unsigned yg = r % 48u;
    const unsigned a  = r / 48u;

    const int c4 = (int)zc * 4;          // z base within row
    const int b0 = (int)yg * HSTEP;      // first y-row
    const int aL = (int)a * LSQ;

    // z-neighbor offsets relative to a row-chunk base (row-invariant)
    const int zmo = (c4 == 0)          ? (LDIM - 1)  : -1;
    const int zpo = (c4 == LDIM - 4)   ? -(LDIM - 4) : 4;

    // x-plane neighbor bases (march with +LDIM per step)
    const int am = (a == 0)        ? (LDIM - 1) : (int)a - 1;
    const int ap = (a == LDIM - 1) ? 0          : (int)a + 1;
    int xmi = am * LSQ + b0 * LDIM + c4;
    int xpi = ap * LSQ + b0 * LDIM + c4;

    const float* __restrict__ x = y;
    const float* __restrict__ p = y + NTOT;

    // ---- preload sliding window: row b0-1 (f4 only) and row b0 (bundle) ----
    const int bm  = (b0 == 0) ? (LDIM - 1) : (b0 - 1);
    const int iym = aL + bm * LDIM + c4;
    f4 ymx = *(const f4*)(x + iym);
    f4 ymp = *(const f4*)(p + iym);

    int ib = aL + b0 * LDIM + c4;
    f4 cx = *(const f4*)(x + ib);  float cxzm = x[ib + zmo], cxzp = x[ib + zpo];
    f4 cp = *(const f4*)(p + ib);  float cpzm = p[ib + zmo], cpzp = p[ib + zpo];

#pragma unroll
    for (int k = 0; k < HSTEP; ++k) {
        const int b  = b0 + k;
        int bn = b + 1; if (bn == LDIM) bn = 0;      // y wrap (only yg==47,k==3)
        const int inx = aL + bn * LDIM + c4;

        // incoming row bundle (yp now, center next step)
        const f4  nx   = *(const f4*)(x + inx);
        const float nxzm = x[inx + zmo], nxzp = x[inx + zpo];
        const f4  np   = *(const f4*)(p + inx);
        const float npzm = p[inx + zmo], npzp = p[inx + zpo];

        // x-plane neighbors for row b
        const f4 xmx = *(const f4*)(x + xmi);
        const f4 xpx = *(const f4*)(x + xpi);
        const f4 xmp = *(const f4*)(p + xmi);
        const f4 xpp = *(const f4*)(p + xpi);

        // per-site params
        const f4 J  = *(const f4*)(Jarr  + ib);
        const f4 an = *(const f4*)(aniso + ib);
        const f4 g  = *(const f4*)(gam   + ib);
        const f4 hx = *(const f4*)(hdx   + ib);
        const f4 hy = *(const f4*)(hdy   + ib);
        const f4 bt = *(const f4*)(beta  + ib);
        const f4 ed = *(const f4*)(edis  + ib);

        // z-direction sums from the center-row registers
        f4 xz, pz;
        xz.x = cxzm + cx.y;  xz.y = cx.x + cx.z;
        xz.z = cx.y + cx.w;  xz.w = cx.z + cxzp;
        pz.x = cpzm + cp.y;  pz.y = cp.x + cp.z;
        pz.z = cp.y + cp.w;  pz.w = cp.z + cpzp;

        const f4 xL = J * ((xmx + xpx + ymx + nx) + an * xz);
        const f4 yL = J * ((xmp + xpp + ymp + np) + an * pz);

        const f4 r2    = cx * cx + cp * cp;
        const f4 cross = xL * cp - yL * cx;

        const f4 dx =  g * cp * cross + ed * cp - yL + hy + bt * r2 * cp;
        const f4 dp = -(g * cx * cross) - ed * cx + xL - hx - bt * r2 * cx;

        *(f4*)(out + ib)        = dx;
        *(f4*)(out + NTOT + ib) = dp;

        // slide the window
        ymx = cx;  ymp = cp;
        cx = nx;   cxzm = nxzm;  cxzp = nxzp;
        cp = np;   cpzm = npzm;  cpzp = npzp;
        ib  += LDIM;
        xmi += LDIM;
        xpi += LDIM;
    }
}

extern "C" void kernel_launch(void* const* d_in, const int* in_sizes, int n_in,
                              void* d_out, int out_size, void* d_ws, size_t ws_size,
                              hipStream_t stream) {
    const float* y_    = (const float*)d_in[1];
    const float* Jarr  = (const float*)d_in[2];
    const float* aniso = (const float*)d_in[3];
    const float* gam   = (const float*)d_in[4];
    const float* hdx   = (const float*)d_in[5];
    const float* hdy   = (const float*)d_in[6];
    const float* beta  = (const float*)d_in[7];
    const float* edis  = (const float*)d_in[8];
    float* out = (float*)d_out;

    dgpe_kernel<<<NBLK, 256, 0, stream>>>(y_, Jarr, aniso, gam, hdx, hdy,
                                          beta, edis, out);
}

// Round 5
// 356.927 us; speedup vs baseline: 1.0272x; 1.0272x over previous
//
#include <hip/hip_runtime.h>

// DGPE ODE RHS, 6-point periodic stencil on 192^3 lattice, fp32.
// R5: float4 along z, NATURAL block order (isolates R3's XCD swizzle —
// suspected cause of the R3 regression). No nontemporal (R2 corruption),
// no y-march (R4 regression: FETCH 127->213 MB, occupancy 44%).

#define LDIM 192
#define LSQ  (LDIM * LDIM)          // 36864
#define NTOT (LDIM * LDIM * LDIM)   // 7077888
#define NQ   (NTOT / 4)             // 1769472 threads (4 sites each)
#define NBLK (NQ / 256)             // 6912 blocks

typedef float f4 __attribute__((ext_vector_type(4)));

__global__ __launch_bounds__(256) void dgpe_kernel(
    const float* __restrict__ y,
    const float* __restrict__ Jarr,
    const float* __restrict__ aniso,
    const float* __restrict__ gam,
    const float* __restrict__ hdx,
    const float* __restrict__ hdy,
    const float* __restrict__ beta,
    const float* __restrict__ edis,
    float* __restrict__ out)
{
    const int t = blockIdx.x * 256 + threadIdx.x;
    const int i = t * 4;                        // base site index (16B-aligned)

    // decompose: t = (a*192 + b)*48 + q, c4 = 4*q
    const unsigned ut  = (unsigned)t;
    const unsigned r   = ut / 48u;              // a*192 + b
    const unsigned c4  = (ut - r * 48u) * 4u;   // z base within row
    const unsigned a   = r / 192u;
    const unsigned b   = r - a * 192u;

    // periodic neighbor base indices (all float4-aligned)
    const int xm = (a == 0)        ? i + (LDIM - 1) * LSQ  : i - LSQ;
    const int xp = (a == LDIM - 1) ? i - (LDIM - 1) * LSQ  : i + LSQ;
    const int ym = (b == 0)        ? i + (LDIM - 1) * LDIM : i - LDIM;
    const int yp = (b == LDIM - 1) ? i - (LDIM - 1) * LDIM : i + LDIM;
    const int rowbase = i - (int)c4;            // a*LSQ + b*LDIM
    const int zmi = (c4 == 0)   ? rowbase + (LDIM - 1) : i - 1;
    const int zpi = (c4 == 188) ? rowbase              : i + 4;

    const float* __restrict__ x = y;
    const float* __restrict__ p = y + NTOT;

    const f4 xc  = *(const f4*)(x + i);
    const f4 xxm = *(const f4*)(x + xm);
    const f4 xxp = *(const f4*)(x + xp);
    const f4 xym = *(const f4*)(x + ym);
    const f4 xyp = *(const f4*)(x + yp);
    const float xzm = x[zmi];
    const float xzp = x[zpi];

    const f4 pc  = *(const f4*)(p + i);
    const f4 pxm = *(const f4*)(p + xm);
    const f4 pxp = *(const f4*)(p + xp);
    const f4 pym = *(const f4*)(p + ym);
    const f4 pyp = *(const f4*)(p + yp);
    const float pzm = p[zmi];
    const float pzp = p[zpi];

    const f4 J  = *(const f4*)(Jarr  + i);
    const f4 an = *(const f4*)(aniso + i);
    const f4 g  = *(const f4*)(gam   + i);
    const f4 hx = *(const f4*)(hdx   + i);
    const f4 hy = *(const f4*)(hdy   + i);
    const f4 bt = *(const f4*)(beta  + i);
    const f4 ed = *(const f4*)(edis  + i);

    // z-direction sums from registers
    f4 xz, pz;
    xz.x = xzm  + xc.y;  xz.y = xc.x + xc.z;
    xz.z = xc.y + xc.w;  xz.w = xc.z + xzp;
    pz.x = pzm  + pc.y;  pz.y = pc.x + pc.z;
    pz.z = pc.y + pc.w;  pz.w = pc.z + pzp;

    const f4 xL = J * ((xxm + xxp + xym + xyp) + an * xz);
    const f4 yL = J * ((pxm + pxp + pym + pyp) + an * pz);

    const f4 r2    = xc * xc + pc * pc;
    const f4 cross = xL * pc - yL * xc;

    const f4 dx =  g * pc * cross + ed * pc - yL + hy + bt * r2 * pc;
    const f4 dp = -(g * xc * cross) - ed * xc + xL - hx - bt * r2 * xc;

    *(f4*)(out + i)        = dx;
    *(f4*)(out + NTOT + i) = dp;
}

extern "C" void kernel_launch(void* const* d_in, const int* in_sizes, int n_in,
                              void* d_out, int out_size, void* d_ws, size_t ws_size,
                              hipStream_t stream) {
    const float* y_    = (const float*)d_in[1];
    const float* Jarr  = (const float*)d_in[2];
    const float* aniso = (const float*)d_in[3];
    const float* gam   = (const float*)d_in[4];
    const float* hdx   = (const float*)d_in[5];
    const float* hdy   = (const float*)d_in[6];
    const float* beta  = (const float*)d_in[7];
    const float* edis  = (const float*)d_in[8];
    float* out = (float*)d_out;

    dgpe_kernel<<<NBLK, 256, 0, stream>>>(y_, Jarr, aniso, gam, hdx, hdy,
                                          beta, edis, out);
}